// Round 13
// baseline (124.633 us; speedup 1.0000x reference)
//
#include <hip/hip_runtime.h>
#include <hip/hip_bf16.h>
#include <hip/hip_cooperative_groups.h>
#include <stdint.h>

namespace cg = cooperative_groups;

#define BATCH 256
#define TSLOT 27
#define NTOT  (BATCH * TSLOT)   // 6912
#define DIM   1024
#define TS    192               // tile size
#define NSMAX 36                // max strips
#define KST   16                // K-steps: 1024 fp8 bytes / 64 B
#define BUFSZ 24576             // per-step LDS: A 12K + B 12K
#define NBUF  6                 // ring depth (144 KB)
#define NBLK  256               // cooperative grid: 1 block per CU

typedef __attribute__((ext_vector_type(4))) float f32x4;
typedef __attribute__((ext_vector_type(2))) long l64x2;

__global__ __launch_bounds__(512, 1)
void fused_kernel(const float* __restrict__ in,
                  const int* __restrict__ tgt,
                  unsigned char* __restrict__ cfb,
                  int* __restrict__ clab,
                  float* __restrict__ Ppos,
                  float* __restrict__ Pneg,
                  float* __restrict__ accum,
                  int* __restrict__ counter,
                  float* __restrict__ out) {
    __shared__ __align__(16) char lds[NBUF * BUFSZ];  // 144 KB (gemm ring / epilogue scratch)
    __shared__ int shs[256];   // inclusive scan of fz
    __shared__ int shf[256];   // fz per sample

    const int tid  = threadIdx.x;
    const int lane = tid & 63;
    const int w    = tid >> 6;         // 0..7
    cg::grid_group grid = cg::this_grid();

    // ================= phase A: scan + compacting row-normalize =================
    if (tid < 256) {
        const int* t = tgt + tid * TSLOT;
        int fz = TSLOT;
        #pragma unroll
        for (int i = TSLOT - 1; i >= 1; --i) fz = (t[i] == 0) ? i : fz;  // first zero
        shf[tid] = fz;
        shs[tid] = fz;
    }
    __syncthreads();
    for (int d = 1; d < 256; d <<= 1) {
        int v = 0;
        if (tid < 256 && tid >= d) v = shs[tid - d];
        __syncthreads();
        if (tid < 256) shs[tid] += v;
        __syncthreads();
    }
    const int nv = shs[255];
    const int npad = ((nv + TS - 1) / TS) * TS;
    const int nstrips = npad / TS;

    if (blockIdx.x == 0) {
        if (tid < 2) accum[tid] = 0.0f;
        if (tid == 2) *counter = 0;
        if (tid < npad - nv) clab[nv + tid] = -1;  // <= TS-1 entries
    }

    // grid-strided row normalize: 2048 waves cover 6912 rows
    for (int wv = blockIdx.x * 8 + w; wv < NTOT; wv += NBLK * 8) {
        const int bb = wv / TSLOT, tt = wv - bb * TSLOT;
        const int fzb = shf[bb];
        if (tt >= fzb) continue;                    // wave-uniform: padded slot
        const int dest = (shs[bb] - fzb) + tt;      // exclusive prefix + slot

        const float* src = in + (size_t)wv * DIM + lane * 16;
        float4 v0 = *(const float4*)(src);
        float4 v1 = *(const float4*)(src + 4);
        float4 v2 = *(const float4*)(src + 8);
        float4 v3 = *(const float4*)(src + 12);
        float ss = v0.x*v0.x + v0.y*v0.y + v0.z*v0.z + v0.w*v0.w
                 + v1.x*v1.x + v1.y*v1.y + v1.z*v1.z + v1.w*v1.w
                 + v2.x*v2.x + v2.y*v2.y + v2.z*v2.z + v2.w*v2.w
                 + v3.x*v3.x + v3.y*v3.y + v3.z*v3.z + v3.w*v3.w;
        #pragma unroll
        for (int off = 1; off < 64; off <<= 1) ss += __shfl_xor(ss, off);
        const float sc = 1.0f / fmaxf(sqrtf(ss), 1e-12f);
        float f[16] = {v0.x,v0.y,v0.z,v0.w, v1.x,v1.y,v1.z,v1.w,
                       v2.x,v2.y,v2.z,v2.w, v3.x,v3.y,v3.z,v3.w};
        uint4 o;
        unsigned int* ow = (unsigned int*)&o;
        #pragma unroll
        for (int q = 0; q < 4; ++q) {
            unsigned int u = 0;
            u = __builtin_amdgcn_cvt_pk_fp8_f32(f[q*4+0] * sc, f[q*4+1] * sc, u, 0);
            u = __builtin_amdgcn_cvt_pk_fp8_f32(f[q*4+2] * sc, f[q*4+3] * sc, u, 1);
            ow[q] = u;
        }
        *(uint4*)(cfb + (size_t)dest * DIM + lane * 16) = o;
        if (lane == 0) clab[dest] = tgt[wv];
    }

    grid.sync();

    // ================= phase B: symmetric fused GEMM over tile loop =================
    {
        const int nact = nstrips * (nstrips + 1) / 2;
        const int x = blockIdx.x & 7, kb0 = blockIdx.x >> 3;   // XCD-chunked mapping
        const int q8 = nact >> 3, r8 = nact & 7;
        const int cnt = q8 + (x < r8 ? 1 : 0);
        const int wm = w >> 2;            // row strip (96 rows)
        const int wn = w & 3;             // col strip (48 cols)
        const int rsel = lane & 15, tsl = lane >> 4;
        const char* fbyte = (const char*)cfb;

        for (int kt = kb0; kt < cnt; kt += 32) {
            int t = x * q8 + (x < r8 ? x : r8) + kt;
            int bi = 0;
            while (t >= nstrips - bi) { t -= nstrips - bi; ++bi; }
            const int bj = bi + t;
            const int row0 = bi * TS;
            const int col0 = bj * TS;
            const bool diag = (bi == bj);

            f32x4 acc[6][3] = {};

            auto stage = [&](int s) {
                char* buf = lds + (s % NBUF) * BUFSZ;
                const int k0b = s * 64;
                #pragma unroll
                for (int j = 0; j < 3; ++j) {
                    const int c = w * 192 + j * 64 + lane;          // 0..1535
                    const int cc = (c >= 768) ? c - 768 : c;
                    const int base = (c >= 768) ? col0 : row0;
                    const int r = cc >> 2, ks = cc & 3;
                    const char* g = fbyte + (size_t)(base + r) * DIM + k0b + ks * 16;
                    __builtin_amdgcn_global_load_lds(
                        (const __attribute__((address_space(1))) void*)g,
                        (__attribute__((address_space(3))) void*)(buf + c * 16),
                        16, 0, 0);
                }
            };
            auto compute = [&](int s) {
                const char* bA = lds + (s % NBUF) * BUFSZ;
                const char* bB = bA + 12288;
                l64x2 av[6], bv[3];
                #pragma unroll
                for (int m = 0; m < 6; ++m) {
                    const int r = wm * 96 + m * 16 + rsel;
                    av[m] = *(const l64x2*)(bA + r * 64 + tsl * 16);
                }
                #pragma unroll
                for (int n = 0; n < 3; ++n) {
                    const int r = wn * 48 + n * 16 + rsel;
                    bv[n] = *(const l64x2*)(bB + r * 64 + tsl * 16);
                }
                #pragma unroll
                for (int kk = 0; kk < 2; ++kk)
                    #pragma unroll
                    for (int m = 0; m < 6; ++m)
                        #pragma unroll
                        for (int n = 0; n < 3; ++n)
                            acc[m][n] = __builtin_amdgcn_mfma_f32_16x16x32_fp8_fp8(
                                av[m][kk], bv[n][kk], acc[m][n], 0, 0, 0);
            };

            stage(0); stage(1); stage(2); stage(3); stage(4);
            #pragma unroll 1
            for (int s = 0; s < KST - 5; ++s) {
                asm volatile("s_waitcnt vmcnt(12)" ::: "memory");
                __builtin_amdgcn_s_barrier();
                asm volatile("" ::: "memory");
                stage(s + 5);
                compute(s);
            }
            asm volatile("s_waitcnt vmcnt(12)" ::: "memory");
            __builtin_amdgcn_s_barrier();
            asm volatile("" ::: "memory");
            compute(KST - 5);
            asm volatile("s_waitcnt vmcnt(9)" ::: "memory");
            __builtin_amdgcn_s_barrier();
            asm volatile("" ::: "memory");
            compute(KST - 4);
            asm volatile("s_waitcnt vmcnt(6)" ::: "memory");
            __builtin_amdgcn_s_barrier();
            asm volatile("" ::: "memory");
            compute(KST - 3);
            asm volatile("s_waitcnt vmcnt(3)" ::: "memory");
            __builtin_amdgcn_s_barrier();
            asm volatile("" ::: "memory");
            compute(KST - 2);
            asm volatile("s_waitcnt vmcnt(0)" ::: "memory");
            __builtin_amdgcn_s_barrier();
            asm volatile("" ::: "memory");
            compute(KST - 1);

            // ---- epilogue: masked exp, cross-wave combine, coalesced stores ----
            const int c = rsel, g = tsl;
            float cpos[3] = {0, 0, 0}, cneg[3] = {0, 0, 0};
            float* fl = (float*)lds;  // buf0: last read by compute(12), all barriered since

            #pragma unroll
            for (int m = 0; m < 6; ++m) {
                #pragma unroll
                for (int rg = 0; rg < 4; ++rg) {
                    const int gi = row0 + wm * 96 + m * 16 + g * 4 + rg;
                    const int li = clab[gi];
                    float rp = 0.0f, rn = 0.0f;
                    #pragma unroll
                    for (int n = 0; n < 3; ++n) {
                        const int gj = col0 + wn * 48 + n * 16 + c;
                        const int lj = clab[gj];
                        const float s = acc[m][n][rg];
                        if (li >= 0 && lj >= 0) {
                            if (li == lj) { float e = __expf(-s); rp += e; cpos[n] += e; }
                            else          { float e = __expf(s);  rn += e; cneg[n] += e; }
                        }
                    }
                    #pragma unroll
                    for (int off = 1; off <= 8; off <<= 1) {
                        rp += __shfl_xor(rp, off);
                        rn += __shfl_xor(rn, off);
                    }
                    if (c == 0) {
                        int lr = m * 16 + g * 4 + rg;          // 0..95
                        fl[w * 96 + lr]        = rp;           // [0, 768)
                        fl[768 + w * 96 + lr]  = rn;           // [768, 1536)
                    }
                }
            }
            #pragma unroll
            for (int n = 0; n < 3; ++n) {
                float p = cpos[n], q = cneg[n];
                p += __shfl_xor(p, 16); p += __shfl_xor(p, 32);
                q += __shfl_xor(q, 16); q += __shfl_xor(q, 32);
                if (g == 0) {
                    int lc = n * 16 + c;                       // 0..47
                    fl[1536 + w * 48 + lc] = p;                // [1536, 1920)
                    fl[1920 + w * 48 + lc] = q;                // [1920, 2304)
                }
            }
            __syncthreads();
            if (tid < 192) {
                int sm = tid / 96, lr = tid % 96;
                float rp = 0.0f, rn = 0.0f;
                #pragma unroll
                for (int kk = 0; kk < 4; ++kk) {
                    rp += fl[(sm * 4 + kk) * 96 + lr];
                    rn += fl[768 + (sm * 4 + kk) * 96 + lr];
                }
                int gi = row0 + tid;
                Ppos[(size_t)bj * NTOT + gi] = rp;   // slot bj (>= bi), coalesced
                Pneg[(size_t)bj * NTOT + gi] = rn;
            } else if (tid < 384 && !diag) {
                int j = tid - 192, cn = j / 48, lc = j % 48;
                float p = fl[1536 + cn * 48 + lc] + fl[1536 + (4 + cn) * 48 + lc];
                float q = fl[1920 + cn * 48 + lc] + fl[1920 + (4 + cn) * 48 + lc];
                int gj = col0 + j;
                Ppos[(size_t)bi * NTOT + gj] = p;    // slot bi (< bj), coalesced
                Pneg[(size_t)bi * NTOT + gj] = q;
            }
            __syncthreads();   // protect lds before next tile's stage()
        }
    }

    grid.sync();

    // ================= phase C: finalize + counter-gated writeout =================
    {
        const int nta = nstrips;
        const int i = blockIdx.x * 512 + tid;
        float s = 0.0f, cnt = 0.0f;
        if (i < npad && clab[i] >= 0) {
            float sp = 0.0f, sn = 0.0f;
            for (int t = 0; t < nta; ++t) {
                sp += Ppos[(size_t)t * NTOT + i];
                sn += Pneg[(size_t)t * NTOT + i];
            }
            s = log1pf(sp * sn);
            cnt = 1.0f;
        }
        #pragma unroll
        for (int off = 1; off < 64; off <<= 1) {
            s   += __shfl_xor(s, off);
            cnt += __shfl_xor(cnt, off);
        }
        __shared__ float sh[16];
        if (lane == 0) { sh[w] = s; sh[8 + w] = cnt; }
        __syncthreads();
        if (tid == 0) {
            float ts = 0.0f, tc = 0.0f;
            #pragma unroll
            for (int k = 0; k < 8; ++k) { ts += sh[k]; tc += sh[8 + k]; }
            if (tc > 0.0f || ts != 0.0f) {
                atomicAdd(&accum[0], ts);
                atomicAdd(&accum[1], tc);
            }
            __threadfence();
            int done = atomicAdd(counter, 1);
            if (done == NBLK - 1) {
                __threadfence();
                out[0] = accum[0] / accum[1];
            }
        }
    }
}

extern "C" void kernel_launch(void* const* d_in, const int* in_sizes, int n_in,
                              void* d_out, int out_size, void* d_ws, size_t ws_size,
                              hipStream_t stream) {
    (void)in_sizes; (void)n_in; (void)out_size; (void)ws_size;
    const float* input_f = (const float*)d_in[0];
    const int*   target  = (const int*)d_in[1];
    float* out = (float*)d_out;

    char* ws = (char*)d_ws;
    const size_t FB_BYTES = (size_t)NTOT * DIM;          // 7,077,888 (fp8)
    unsigned char* cfb = (unsigned char*)ws;
    char* p = ws + FB_BYTES;
    int*   clab    = (int*)p;          p += NTOT * 4;
    float* accum   = (float*)p;        p += 128;
    int*   counter = (int*)p;          p += 128;
    float* Ppos    = (float*)p;        p += (size_t)NSMAX * NTOT * 4;  // 995 KB
    float* Pneg    = (float*)p;

    void* kargs[] = {(void*)&input_f, (void*)&target, (void*)&cfb, (void*)&clab,
                     (void*)&Ppos, (void*)&Pneg, (void*)&accum, (void*)&counter,
                     (void*)&out};
    hipLaunchCooperativeKernel((void*)fused_kernel, dim3(NBLK), dim3(512),
                               kargs, 0, stream);
}

// Round 14
// 49.134 us; speedup vs baseline: 2.5366x; 2.5366x over previous
//
#include <hip/hip_runtime.h>
#include <hip/hip_bf16.h>
#include <stdint.h>

#define BATCH 256
#define TSLOT 27
#define NTOT  (BATCH * TSLOT)   // 6912
#define DIM   1024
#define TS    192               // tile size
#define NSMAX 36                // max strips (NTOT/TS)
#define NTRIMAX (NSMAX * (NSMAX + 1) / 2)  // 666
#define KST   16                // K-steps: 1024 fp8 bytes / 64 B
#define BUFSZ 24576             // per-step LDS: A 12K + B 12K

typedef __attribute__((ext_vector_type(4))) float f32x4;
typedef __attribute__((ext_vector_type(2))) long l64x2;

// ---------- fused prep + norm: every block redundantly computes the sample-length
// scan (targets L2-hot, scan block-local), then 4 waves normalize 4 rows. ----------
__global__ __launch_bounds__(256) void prep_norm_kernel(const float* __restrict__ in,
                                                        const int* __restrict__ tgt,
                                                        unsigned char* __restrict__ cfb,
                                                        int* __restrict__ clab,
                                                        int* __restrict__ meta,
                                                        float* __restrict__ accum,
                                                        int* __restrict__ counter) {
    __shared__ int shs[256];   // inclusive scan of fz
    __shared__ int shf[256];   // fz per sample
    const int b = threadIdx.x;
    {
        const int* t = tgt + b * TSLOT;
        int fz = TSLOT;
        #pragma unroll
        for (int i = TSLOT - 1; i >= 1; --i) fz = (t[i] == 0) ? i : fz;  // first zero
        shf[b] = fz;
        shs[b] = fz;
    }
    __syncthreads();
    for (int d = 1; d < 256; d <<= 1) {
        int v = (b >= d) ? shs[b - d] : 0;
        __syncthreads();
        shs[b] += v;
        __syncthreads();
    }
    const int nv = shs[255];
    const int npad = ((nv + TS - 1) / TS) * TS;

    if (blockIdx.x == 0) {
        if (b < 2) accum[b] = 0.0f;
        if (b == 2) *counter = 0;
        if (b == 3) { meta[0] = nv; meta[1] = npad; }
        if (b < npad - nv) clab[nv + b] = -1;  // <= TS-1 entries
    }

    const int wv   = blockIdx.x * 4 + (threadIdx.x >> 6);
    const int lane = threadIdx.x & 63;
    const int bb = wv / TSLOT, tt = wv - bb * TSLOT;
    const int fzb = shf[bb];
    if (tt >= fzb) return;                      // wave-uniform: padded slot
    const int dest = (shs[bb] - fzb) + tt;      // exclusive prefix + slot

    const float* src = in + (size_t)wv * DIM + lane * 16;
    float4 v0 = *(const float4*)(src);
    float4 v1 = *(const float4*)(src + 4);
    float4 v2 = *(const float4*)(src + 8);
    float4 v3 = *(const float4*)(src + 12);
    float ss = v0.x*v0.x + v0.y*v0.y + v0.z*v0.z + v0.w*v0.w
             + v1.x*v1.x + v1.y*v1.y + v1.z*v1.z + v1.w*v1.w
             + v2.x*v2.x + v2.y*v2.y + v2.z*v2.z + v2.w*v2.w
             + v3.x*v3.x + v3.y*v3.y + v3.z*v3.z + v3.w*v3.w;
    #pragma unroll
    for (int off = 1; off < 64; off <<= 1) ss += __shfl_xor(ss, off);
    const float sc = 1.0f / fmaxf(sqrtf(ss), 1e-12f);
    float f[16] = {v0.x,v0.y,v0.z,v0.w, v1.x,v1.y,v1.z,v1.w,
                   v2.x,v2.y,v2.z,v2.w, v3.x,v3.y,v3.z,v3.w};
    uint4 o;
    unsigned int* ow = (unsigned int*)&o;
    #pragma unroll
    for (int q = 0; q < 4; ++q) {
        unsigned int u = 0;
        u = __builtin_amdgcn_cvt_pk_fp8_f32(f[q*4+0] * sc, f[q*4+1] * sc, u, 0);
        u = __builtin_amdgcn_cvt_pk_fp8_f32(f[q*4+2] * sc, f[q*4+3] * sc, u, 1);
        ow[q] = u;
    }
    *(uint4*)(cfb + (size_t)dest * DIM + lane * 16) = o;
    if (lane == 0) clab[dest] = tgt[wv];
}

// ---------- symmetric fused GEMM: fp8, 192-tile, 8 waves, 4-buf depth-3 ----------
// Linear LDS addressing: 64-B rows make every wave's b128 fragment read a
// contiguous 1-KB region (each bank exactly 8 words = HW minimum) and every
// staging instruction a contiguous 1-KB write -> conflict-free, no swizzle.
__global__ __launch_bounds__(512) void gemm_kernel(const unsigned char* __restrict__ fb,
                                                   const int* __restrict__ clab,
                                                   const int* __restrict__ meta,
                                                   float* __restrict__ Ppos,
                                                   float* __restrict__ Pneg) {
    __shared__ __align__(16) char lds[4 * BUFSZ];  // 96 KB

    const int npad = meta[1];
    const int nstrips = npad / TS;
    const int nact = nstrips * (nstrips + 1) / 2;
    const int k = blockIdx.x >> 3, x = blockIdx.x & 7;
    const int q8 = nact >> 3, r8 = nact & 7;
    const int cnt = q8 + (x < r8 ? 1 : 0);
    if (k >= cnt) return;
    int t = x * q8 + (x < r8 ? x : r8) + k;
    int bi = 0;
    while (t >= nstrips - bi) { t -= nstrips - bi; ++bi; }
    const int bj = bi + t;
    const int row0 = bi * TS;
    const int col0 = bj * TS;
    const bool diag = (bi == bj);

    const int tid  = threadIdx.x;
    const int lane = tid & 63;
    const int w    = tid >> 6;         // 0..7
    const int wm   = w >> 2;           // row strip (96 rows)
    const int wn   = w & 3;            // col strip (48 cols)

    f32x4 acc[6][3] = {};
    const char* fbyte = (const char*)fb;

    auto stage = [&](int s) {
        char* buf = lds + (s & 3) * BUFSZ;
        const int k0b = s * 64;
        #pragma unroll
        for (int j = 0; j < 3; ++j) {
            const int c = w * 192 + j * 64 + lane;          // 0..1535
            const int cc = (c >= 768) ? c - 768 : c;
            const int base = (c >= 768) ? col0 : row0;
            const int r = cc >> 2, ks = cc & 3;
            const char* g = fbyte + (size_t)(base + r) * DIM + k0b + ks * 16;
            __builtin_amdgcn_global_load_lds(
                (const __attribute__((address_space(1))) void*)g,
                (__attribute__((address_space(3))) void*)(buf + c * 16),
                16, 0, 0);
        }
    };

    const int rsel = lane & 15, tsl = lane >> 4;
    auto compute = [&](int s) {
        const char* bA = lds + (s & 3) * BUFSZ;
        const char* bB = bA + 12288;
        l64x2 av[6], bv[3];
        #pragma unroll
        for (int m = 0; m < 6; ++m) {
            const int r = wm * 96 + m * 16 + rsel;
            av[m] = *(const l64x2*)(bA + r * 64 + tsl * 16);
        }
        #pragma unroll
        for (int n = 0; n < 3; ++n) {
            const int r = wn * 48 + n * 16 + rsel;
            bv[n] = *(const l64x2*)(bB + r * 64 + tsl * 16);
        }
        #pragma unroll
        for (int kk = 0; kk < 2; ++kk)
            #pragma unroll
            for (int m = 0; m < 6; ++m)
                #pragma unroll
                for (int n = 0; n < 3; ++n)
                    acc[m][n] = __builtin_amdgcn_mfma_f32_16x16x32_fp8_fp8(
                        av[m][kk], bv[n][kk], acc[m][n], 0, 0, 0);
    };

    stage(0); stage(1); stage(2);  // 9 loads/wave outstanding
    #pragma unroll 1
    for (int s = 0; s < KST - 3; ++s) {
        asm volatile("s_waitcnt vmcnt(6)" ::: "memory");   // own stage s landed
        __builtin_amdgcn_s_barrier();                      // all waves' stage s landed
        asm volatile("" ::: "memory");
        stage(s + 3);                                      // buf (s-1)&3: all past compute(s-1)
        compute(s);
    }
    asm volatile("s_waitcnt vmcnt(6)" ::: "memory");
    __builtin_amdgcn_s_barrier();
    asm volatile("" ::: "memory");
    compute(KST - 3);
    asm volatile("s_waitcnt vmcnt(3)" ::: "memory");
    __builtin_amdgcn_s_barrier();
    asm volatile("" ::: "memory");
    compute(KST - 2);
    asm volatile("s_waitcnt vmcnt(0)" ::: "memory");
    __builtin_amdgcn_s_barrier();
    asm volatile("" ::: "memory");
    compute(KST - 1);

    // ---- epilogue: masked exp, cross-wave combine through LDS, coalesced stores ----
    const int c = rsel, g = tsl;
    float cpos[3] = {0, 0, 0}, cneg[3] = {0, 0, 0};
    float* fl = (float*)lds;  // buf0: last read by compute(12), all waves barriered since

    #pragma unroll
    for (int m = 0; m < 6; ++m) {
        #pragma unroll
        for (int rg = 0; rg < 4; ++rg) {
            const int gi = row0 + wm * 96 + m * 16 + g * 4 + rg;
            const int li = clab[gi];
            float rp = 0.0f, rn = 0.0f;
            #pragma unroll
            for (int n = 0; n < 3; ++n) {
                const int gj = col0 + wn * 48 + n * 16 + c;
                const int lj = clab[gj];
                const float s = acc[m][n][rg];
                if (li >= 0 && lj >= 0) {
                    if (li == lj) { float e = __expf(-s); rp += e; cpos[n] += e; }
                    else          { float e = __expf(s);  rn += e; cneg[n] += e; }
                }
            }
            #pragma unroll
            for (int off = 1; off <= 8; off <<= 1) {
                rp += __shfl_xor(rp, off);
                rn += __shfl_xor(rn, off);
            }
            if (c == 0) {
                int lr = m * 16 + g * 4 + rg;          // 0..95
                fl[w * 96 + lr]        = rp;           // [0, 768)
                fl[768 + w * 96 + lr]  = rn;           // [768, 1536)
            }
        }
    }
    #pragma unroll
    for (int n = 0; n < 3; ++n) {
        float p = cpos[n], q = cneg[n];
        p += __shfl_xor(p, 16); p += __shfl_xor(p, 32);
        q += __shfl_xor(q, 16); q += __shfl_xor(q, 32);
        if (g == 0) {
            int lc = n * 16 + c;                       // 0..47
            fl[1536 + w * 48 + lc] = p;                // [1536, 1920)
            fl[1920 + w * 48 + lc] = q;                // [1920, 2304)
        }
    }
    __syncthreads();
    if (tid < 192) {
        int sm = tid / 96, lr = tid % 96;
        float rp = 0.0f, rn = 0.0f;
        #pragma unroll
        for (int kk = 0; kk < 4; ++kk) {
            rp += fl[(sm * 4 + kk) * 96 + lr];
            rn += fl[768 + (sm * 4 + kk) * 96 + lr];
        }
        int gi = row0 + tid;
        Ppos[(size_t)bj * NTOT + gi] = rp;   // slot bj (>= bi), coalesced
        Pneg[(size_t)bj * NTOT + gi] = rn;
    } else if (tid < 384 && !diag) {
        int j = tid - 192, cn = j / 48, lc = j % 48;
        float p = fl[1536 + cn * 48 + lc] + fl[1536 + (4 + cn) * 48 + lc];
        float q = fl[1920 + cn * 48 + lc] + fl[1920 + (4 + cn) * 48 + lc];
        int gj = col0 + j;
        Ppos[(size_t)bi * NTOT + gj] = p;    // slot bi (< bj), coalesced
        Pneg[(size_t)bi * NTOT + gj] = q;
    }
}

// ---------- finalize: gather partials, masked mean, last block writes out ----------
__global__ __launch_bounds__(256) void finalize_kernel(const int* __restrict__ clab,
                                                       const int* __restrict__ meta,
                                                       const float* __restrict__ Ppos,
                                                       const float* __restrict__ Pneg,
                                                       float* __restrict__ accum,
                                                       int* __restrict__ counter,
                                                       float* __restrict__ out) {
    int i = blockIdx.x * blockDim.x + threadIdx.x;
    const int npad = meta[1];
    const int nta = npad / TS;
    float s = 0.0f, cnt = 0.0f;
    if (i < npad && clab[i] >= 0) {
        float sp = 0.0f, sn = 0.0f;
        for (int t = 0; t < nta; ++t) {
            sp += Ppos[(size_t)t * NTOT + i];
            sn += Pneg[(size_t)t * NTOT + i];
        }
        s = log1pf(sp * sn);
        cnt = 1.0f;
    }
    #pragma unroll
    for (int off = 1; off < 64; off <<= 1) {
        s   += __shfl_xor(s, off);
        cnt += __shfl_xor(cnt, off);
    }
    __shared__ float sh[8];
    int lane = threadIdx.x & 63, w = threadIdx.x >> 6;
    if (lane == 0) { sh[w] = s; sh[4 + w] = cnt; }
    __syncthreads();
    if (threadIdx.x == 0) {
        atomicAdd(&accum[0], sh[0] + sh[1] + sh[2] + sh[3]);
        atomicAdd(&accum[1], sh[4] + sh[5] + sh[6] + sh[7]);
        __threadfence();
        int done = atomicAdd(counter, 1);
        if (done == (int)gridDim.x - 1) {
            __threadfence();
            out[0] = accum[0] / accum[1];
        }
    }
}

extern "C" void kernel_launch(void* const* d_in, const int* in_sizes, int n_in,
                              void* d_out, int out_size, void* d_ws, size_t ws_size,
                              hipStream_t stream) {
    (void)in_sizes; (void)n_in; (void)out_size; (void)ws_size;
    const float* input_f = (const float*)d_in[0];
    const int*   target  = (const int*)d_in[1];
    float* out = (float*)d_out;

    char* ws = (char*)d_ws;
    const size_t FB_BYTES = (size_t)NTOT * DIM;          // 7,077,888 (fp8)
    unsigned char* cfb = (unsigned char*)ws;
    char* p = ws + FB_BYTES;
    int*   clab    = (int*)p;          p += NTOT * 4;
    int*   meta    = (int*)p;          p += 256;
    float* accum   = (float*)p;        p += 128;
    int*   counter = (int*)p;          p += 128;
    float* Ppos    = (float*)p;        p += (size_t)NSMAX * NTOT * 4;  // 995 KB
    float* Pneg    = (float*)p;

    prep_norm_kernel<<<dim3(NTOT / 4), dim3(256), 0, stream>>>(input_f, target, cfb, clab, meta, accum, counter);
    gemm_kernel<<<dim3(NTRIMAX), dim3(512), 0, stream>>>(cfb, clab, meta, Ppos, Pneg);
    finalize_kernel<<<dim3((NTOT + 255) / 256), dim3(256), 0, stream>>>(clab, meta, Ppos, Pneg, accum, counter, out);
}